// Round 1
// baseline (159.000 us; speedup 1.0000x reference)
//
#include <hip/hip_runtime.h>

// Problem constants: pred [1,4,2048,2048] fp32, true [2048,2048] int32 (labels 0..3)
static constexpr int HW   = 2048 * 2048;   // pixels
static constexpr int NQ   = HW / 4;        // float4 / int4 quads
static constexpr int NBLK = 1024;
static constexpr int NTHR = 256;

// d_ws counter layout (unsigned int):
//  [0..3]  p_sum per class (argmax==c)
//  [4..7]  t_sum per class (true==c)
//  [8..11] inter per class (argmax==c && true==c)

__global__ void zero_ws_kernel(unsigned int* __restrict__ cnt) {
    int i = threadIdx.x;
    if (i < 12) cnt[i] = 0u;
}

__global__ __launch_bounds__(NTHR) void count_kernel(const float* __restrict__ pred,
                                                     const int* __restrict__ lbl,
                                                     unsigned int* __restrict__ cnt) {
    const float4* __restrict__ p0 = (const float4*)(pred);
    const float4* __restrict__ p1 = (const float4*)(pred + (size_t)HW);
    const float4* __restrict__ p2 = (const float4*)(pred + (size_t)2 * HW);
    const float4* __restrict__ p3 = (const float4*)(pred + (size_t)3 * HW);
    const int4*   __restrict__ tl = (const int4*)(lbl);

    // byte-packed per-thread counters: 8-bit lane per class (max 16 pixels/thread, no overflow)
    unsigned int pc = 0u, tc = 0u, ic = 0u;

    for (int i = blockIdx.x * NTHR + threadIdx.x; i < NQ; i += gridDim.x * NTHR) {
        float4 a = p0[i];
        float4 b = p1[i];
        float4 c = p2[i];
        float4 d = p3[i];
        int4   t = tl[i];

        float a_[4] = {a.x, a.y, a.z, a.w};
        float b_[4] = {b.x, b.y, b.z, b.w};
        float c_[4] = {c.x, c.y, c.z, c.w};
        float d_[4] = {d.x, d.y, d.z, d.w};
        int   t_[4] = {t.x, t.y, t.z, t.w};

#pragma unroll
        for (int j = 0; j < 4; ++j) {
            // jnp.argmax tie-break: first (lowest) index among maxima -> strict '>'
            float best = a_[j];
            int   pi   = 0;
            if (b_[j] > best) { best = b_[j]; pi = 1; }
            if (c_[j] > best) { best = c_[j]; pi = 2; }
            if (d_[j] > best) { best = d_[j]; pi = 3; }
            int tj = t_[j];
            pc += 1u << (pi * 8);
            tc += 1u << (tj * 8);
            ic += (pi == tj) ? (1u << (pi * 8)) : 0u;
        }
    }

    // widen 8-bit lanes -> two u32 with 16-bit lanes (classes {0,2} in lo, {1,3} in hi)
    unsigned int plo = pc & 0x00FF00FFu, phi = (pc >> 8) & 0x00FF00FFu;
    unsigned int tlo = tc & 0x00FF00FFu, thi = (tc >> 8) & 0x00FF00FFu;
    unsigned int ilo = ic & 0x00FF00FFu, ihi = (ic >> 8) & 0x00FF00FFu;

    // wave-64 reduction (16-bit lanes: max 64*16=1024 per lane, no overflow)
#pragma unroll
    for (int off = 32; off > 0; off >>= 1) {
        plo += __shfl_down(plo, off);
        phi += __shfl_down(phi, off);
        tlo += __shfl_down(tlo, off);
        thi += __shfl_down(thi, off);
        ilo += __shfl_down(ilo, off);
        ihi += __shfl_down(ihi, off);
    }

    __shared__ unsigned int red[NTHR / 64][6];
    int wave = threadIdx.x >> 6;
    int lane = threadIdx.x & 63;
    if (lane == 0) {
        red[wave][0] = plo; red[wave][1] = phi;
        red[wave][2] = tlo; red[wave][3] = thi;
        red[wave][4] = ilo; red[wave][5] = ihi;
    }
    __syncthreads();

    if (threadIdx.x == 0) {
        unsigned int s[6];
#pragma unroll
        for (int k = 0; k < 6; ++k) {
            unsigned int acc = 0;
#pragma unroll
            for (int w = 0; w < NTHR / 64; ++w) acc += red[w][k];
            s[k] = acc;  // 16-bit lanes: max 4*1024 = 4096, no overflow
        }
        // s = {plo, phi, tlo, thi, ilo, ihi}; lane0 = class{0}, lane1 = class{2} etc.
        atomicAdd(&cnt[0],  s[0] & 0xFFFFu);  // p0
        atomicAdd(&cnt[2],  s[0] >> 16);      // p2
        atomicAdd(&cnt[1],  s[1] & 0xFFFFu);  // p1
        atomicAdd(&cnt[3],  s[1] >> 16);      // p3
        atomicAdd(&cnt[4],  s[2] & 0xFFFFu);  // t0
        atomicAdd(&cnt[6],  s[2] >> 16);      // t2
        atomicAdd(&cnt[5],  s[3] & 0xFFFFu);  // t1
        atomicAdd(&cnt[7],  s[3] >> 16);      // t3
        atomicAdd(&cnt[8],  s[4] & 0xFFFFu);  // i0
        atomicAdd(&cnt[10], s[4] >> 16);      // i2
        atomicAdd(&cnt[9],  s[5] & 0xFFFFu);  // i1
        atomicAdd(&cnt[11], s[5] >> 16);      // i3
    }
}

__global__ void finalize_kernel(const unsigned int* __restrict__ cnt,
                                float* __restrict__ out) {
    if (blockIdx.x != 0 || threadIdx.x != 0) return;
    const float S = 1e-5f;
    float p[4], t[4], in[4];
    float sp = 0.f, st = 0.f;
#pragma unroll
    for (int c = 0; c < 4; ++c) {
        p[c]  = (float)cnt[c];
        t[c]  = (float)cnt[4 + c];
        in[c] = (float)cnt[8 + c];
        sp += p[c];
        st += t[c];
    }
    float total = sp + st;  // == p1h.sum() + t1h.sum()
    float dsum = 0.f, isum = 0.f;
    int npres = 0;
#pragma unroll
    for (int c = 0; c < 4; ++c) {
        if (cnt[4 + c] > 0u) {  // class present in `true`
            ++npres;
            dsum += 1.0f - (2.0f * in[c] + S) / (p[c] + t[c] + S);
            isum += 1.0f - (in[c] + S) / (total + S - in[c]);
        }
    }
    float n = (float)(npres > 0 ? npres : 1);
    out[0] = dsum / n + isum / n;
}

extern "C" void kernel_launch(void* const* d_in, const int* in_sizes, int n_in,
                              void* d_out, int out_size, void* d_ws, size_t ws_size,
                              hipStream_t stream) {
    const float* pred = (const float*)d_in[0];
    const int*   lbl  = (const int*)d_in[1];
    float*       out  = (float*)d_out;
    unsigned int* cnt = (unsigned int*)d_ws;

    zero_ws_kernel<<<1, 64, 0, stream>>>(cnt);
    count_kernel<<<NBLK, NTHR, 0, stream>>>(pred, lbl, cnt);
    finalize_kernel<<<1, 64, 0, stream>>>(cnt, out);
}

// Round 2
// 24.907 us; speedup vs baseline: 6.3837x; 6.3837x over previous
//
#include <hip/hip_runtime.h>

// Problem constants: pred [1,4,2048,2048] fp32, true [2048,2048] int32 (labels 0..3)
static constexpr int HW   = 2048 * 2048;   // pixels
static constexpr int NQ   = HW / 4;        // float4 / int4 quads
static constexpr int NBLK = 2048;
static constexpr int NTHR = 256;
static constexpr int QPT  = NQ / (NBLK * NTHR);  // = 2 quads (8 pixels) per thread

// d_ws layout: unsigned int partial[NBLK][12]
//  [0..3]  p_sum per class (argmax==c)
//  [4..7]  t_sum per class (true==c)
//  [8..11] inter per class (argmax==c && true==c)

__global__ __launch_bounds__(NTHR) void count_kernel(const float* __restrict__ pred,
                                                     const int* __restrict__ lbl,
                                                     unsigned int* __restrict__ partial) {
    const float4* __restrict__ p0 = (const float4*)(pred);
    const float4* __restrict__ p1 = (const float4*)(pred + (size_t)HW);
    const float4* __restrict__ p2 = (const float4*)(pred + (size_t)2 * HW);
    const float4* __restrict__ p3 = (const float4*)(pred + (size_t)3 * HW);
    const int4*   __restrict__ tl = (const int4*)(lbl);

    // byte-packed per-thread counters: 8-bit lane per class (max 8 pixels/thread)
    unsigned int pc = 0u, tc = 0u, ic = 0u;

    const int base = blockIdx.x * NTHR + threadIdx.x;
#pragma unroll
    for (int q = 0; q < QPT; ++q) {
        const int i = base + q * (NBLK * NTHR);
        float4 a = p0[i];
        float4 b = p1[i];
        float4 c = p2[i];
        float4 d = p3[i];
        int4   t = tl[i];

        float a_[4] = {a.x, a.y, a.z, a.w};
        float b_[4] = {b.x, b.y, b.z, b.w};
        float c_[4] = {c.x, c.y, c.z, c.w};
        float d_[4] = {d.x, d.y, d.z, d.w};
        int   t_[4] = {t.x, t.y, t.z, t.w};

#pragma unroll
        for (int j = 0; j < 4; ++j) {
            // jnp.argmax tie-break: first (lowest) index among maxima -> strict '>'
            float best = a_[j];
            int   pi   = 0;
            if (b_[j] > best) { best = b_[j]; pi = 1; }
            if (c_[j] > best) { best = c_[j]; pi = 2; }
            if (d_[j] > best) { best = d_[j]; pi = 3; }
            int tj = t_[j];
            pc += 1u << (pi * 8);
            tc += 1u << (tj * 8);
            ic += (pi == tj) ? (1u << (pi * 8)) : 0u;
        }
    }

    // widen 8-bit lanes -> two u32 with 16-bit lanes (classes {0,2} in lo, {1,3} in hi)
    unsigned int plo = pc & 0x00FF00FFu, phi = (pc >> 8) & 0x00FF00FFu;
    unsigned int tlo = tc & 0x00FF00FFu, thi = (tc >> 8) & 0x00FF00FFu;
    unsigned int ilo = ic & 0x00FF00FFu, ihi = (ic >> 8) & 0x00FF00FFu;

    // wave-64 reduction (16-bit lanes: max 64*8=512 per lane, no overflow)
#pragma unroll
    for (int off = 32; off > 0; off >>= 1) {
        plo += __shfl_down(plo, off);
        phi += __shfl_down(phi, off);
        tlo += __shfl_down(tlo, off);
        thi += __shfl_down(thi, off);
        ilo += __shfl_down(ilo, off);
        ihi += __shfl_down(ihi, off);
    }

    __shared__ unsigned int red[NTHR / 64][6];
    int wave = threadIdx.x >> 6;
    int lane = threadIdx.x & 63;
    if (lane == 0) {
        red[wave][0] = plo; red[wave][1] = phi;
        red[wave][2] = tlo; red[wave][3] = thi;
        red[wave][4] = ilo; red[wave][5] = ihi;
    }
    __syncthreads();

    if (threadIdx.x == 0) {
        unsigned int s[6];
#pragma unroll
        for (int k = 0; k < 6; ++k) {
            unsigned int acc = 0;
#pragma unroll
            for (int w = 0; w < NTHR / 64; ++w) acc += red[w][k];
            s[k] = acc;  // 16-bit lanes: max 4*512 = 2048, no overflow
        }
        unsigned int* out = partial + (size_t)blockIdx.x * 12;
        // s = {plo, phi, tlo, thi, ilo, ihi}; lo16 = class{0 or 1}, hi16 = class{2 or 3}
        out[0]  = s[0] & 0xFFFFu;  // p0
        out[1]  = s[1] & 0xFFFFu;  // p1
        out[2]  = s[0] >> 16;      // p2
        out[3]  = s[1] >> 16;      // p3
        out[4]  = s[2] & 0xFFFFu;  // t0
        out[5]  = s[3] & 0xFFFFu;  // t1
        out[6]  = s[2] >> 16;      // t2
        out[7]  = s[3] >> 16;      // t3
        out[8]  = s[4] & 0xFFFFu;  // i0
        out[9]  = s[5] & 0xFFFFu;  // i1
        out[10] = s[4] >> 16;      // i2
        out[11] = s[5] >> 16;      // i3
    }
}

__global__ __launch_bounds__(NTHR) void finalize_kernel(const unsigned int* __restrict__ partial,
                                                        float* __restrict__ out) {
    unsigned int s[12];
#pragma unroll
    for (int k = 0; k < 12; ++k) s[k] = 0u;

    for (int b = threadIdx.x; b < NBLK; b += NTHR) {
        const unsigned int* src = partial + (size_t)b * 12;
#pragma unroll
        for (int k = 0; k < 12; ++k) s[k] += src[k];
    }

    // wave reduce each of the 12 sums
#pragma unroll
    for (int off = 32; off > 0; off >>= 1) {
#pragma unroll
        for (int k = 0; k < 12; ++k) s[k] += __shfl_down(s[k], off);
    }

    __shared__ unsigned int red[NTHR / 64][12];
    int wave = threadIdx.x >> 6;
    int lane = threadIdx.x & 63;
    if (lane == 0) {
#pragma unroll
        for (int k = 0; k < 12; ++k) red[wave][k] = s[k];
    }
    __syncthreads();

    if (threadIdx.x == 0) {
        float p[4], t[4], in[4];
        float sp = 0.f, st = 0.f;
        unsigned int tot[12];
#pragma unroll
        for (int k = 0; k < 12; ++k) {
            unsigned int acc = 0;
#pragma unroll
            for (int w = 0; w < NTHR / 64; ++w) acc += red[w][k];
            tot[k] = acc;
        }
#pragma unroll
        for (int c = 0; c < 4; ++c) {
            p[c]  = (float)tot[c];
            t[c]  = (float)tot[4 + c];
            in[c] = (float)tot[8 + c];
            sp += p[c];
            st += t[c];
        }
        const float S = 1e-5f;
        float total = sp + st;  // == p1h.sum() + t1h.sum()
        float dsum = 0.f, isum = 0.f;
        int npres = 0;
#pragma unroll
        for (int c = 0; c < 4; ++c) {
            if (tot[4 + c] > 0u) {  // class present in `true`
                ++npres;
                dsum += 1.0f - (2.0f * in[c] + S) / (p[c] + t[c] + S);
                isum += 1.0f - (in[c] + S) / (total + S - in[c]);
            }
        }
        float n = (float)(npres > 0 ? npres : 1);
        out[0] = dsum / n + isum / n;
    }
}

extern "C" void kernel_launch(void* const* d_in, const int* in_sizes, int n_in,
                              void* d_out, int out_size, void* d_ws, size_t ws_size,
                              hipStream_t stream) {
    const float* pred = (const float*)d_in[0];
    const int*   lbl  = (const int*)d_in[1];
    float*       out  = (float*)d_out;
    unsigned int* partial = (unsigned int*)d_ws;   // NBLK * 12 u32 = 96 KB

    count_kernel<<<NBLK, NTHR, 0, stream>>>(pred, lbl, partial);
    finalize_kernel<<<1, NTHR, 0, stream>>>(partial, out);
}